// Round 7
// baseline (168.755 us; speedup 1.0000x reference)
//
#include <hip/hip_runtime.h>

#define C 161
#define C3 4173281            // 161^3 cells
#define NVERT_ELEMS 12519843  // C3*3
#define APQ 4121600           // 161*160*160 quads per axis
#define TQ 12364800           // 3*APQ
#define TOTQ_ELEMS 49459200   // 4*TQ
#define NVB 16302             // ceil(C3/256)
#define NW 3091200            // ceil((TOTQ_ELEMS-1)/16) windows of 16 elems
#define NWB 12075             // NW/256

// round f32 to nearest bf16 (RNE), return as f32
__device__ __forceinline__ float bf16r(float f) {
    union { float f; unsigned int u; } v; v.f = f;
    v.u += 0x7FFFu + ((v.u >> 16) & 1u);
    v.u &= 0xFFFF0000u;
    return v.f;
}

// general clamped sample of padded grid (pad 1.0); x,y,z padded coords
__device__ __forceinline__ float sampg(const float* __restrict__ g, int x, int y, int z) {
    int ux = x - 1, uy = y - 1, uz = z - 1;
    bool in = ((unsigned)ux < 160u) && ((unsigned)uy < 160u) && ((unsigned)uz < 160u);
    int cx = min(max(ux, 0), 159);
    int cy = min(max(uy, 0), 159);
    int cz = min(max(uz, 0), 159);
    float v = g[(cx * 160 + cy) * 160 + cz];
    return in ? v : 1.0f;
}

__global__ __launch_bounds__(256) void verts_kernel(const float* __restrict__ grid,
                                                    const float* __restrict__ deform,
                                                    float* __restrict__ out) {
    __shared__ __align__(16) float sv[768];
    int tid = blockIdx.x * 256 + threadIdx.x;
    int cz = tid % C;
    int t2 = tid / C;
    int cy = t2 % C;
    int cx = t2 / C;

    float gv[8], px[8], py[8], pz[8];
    // wave-uniform fast path: every lane's 8 corners strictly in-bounds
    bool interior = ((unsigned)(cx - 1) < 159u) & ((unsigned)(cy - 1) < 159u) &
                    ((unsigned)(cz - 1) < 159u);
    if (__all(interior)) {
        int base = ((cx - 1) * 160 + (cy - 1)) * 160 + (cz - 1);
#pragma unroll
        for (int c = 0; c < 8; ++c) {
            int bx = (c >> 2) & 1, by = (c >> 1) & 1, bz = c & 1;
            int idx = base + bx * 25600 + by * 160 + bz;
            gv[c] = grid[idx];
            const float* p = deform + (size_t)idx * 3;
            px[c] = (float)(cx + bx) + p[0];
            py[c] = (float)(cy + by) + p[1];
            pz[c] = (float)(cz + bz) + p[2];
        }
    } else {
#pragma unroll
        for (int c = 0; c < 8; ++c) {
            int bx = (c >> 2) & 1, by = (c >> 1) & 1, bz = c & 1;
            int x = cx + bx, y = cy + by, z = cz + bz;
            gv[c] = sampg(grid, x, y, z);
            int ux = x - 1, uy = y - 1, uz = z - 1;
            bool in = ((unsigned)ux < 160u) && ((unsigned)uy < 160u) && ((unsigned)uz < 160u);
            int ix = min(max(ux, 0), 159);
            int iy = min(max(uy, 0), 159);
            int iz = min(max(uz, 0), 159);
            const float* p = deform + ((size_t)((ix * 160 + iy) * 160 + iz)) * 3;
            float a0 = p[0], a1 = p[1], a2 = p[2];
            px[c] = (float)x + (in ? a0 : 0.f);
            py[c] = (float)y + (in ? a1 : 0.f);
            pz[c] = (float)z + (in ? a2 : 0.f);
        }
    }

    float vs0 = 0.f, vs1 = 0.f, vs2 = 0.f, cnt = 0.f;
#pragma unroll
    for (int a = 0; a < 3; ++a) {
        int step = (a == 0) ? 4 : ((a == 1) ? 2 : 1);
#pragma unroll
        for (int c = 0; c < 8; ++c) {
            if (c & step) continue;
            int c1 = c | step;
            float g0 = gv[c], g1 = gv[c1];
            if ((g0 < 0.f) != (g1 < 0.f)) {
                float tt = g0 * __builtin_amdgcn_rcpf(g0 - g1);
                vs0 += px[c] + tt * (px[c1] - px[c]);
                vs1 += py[c] + tt * (py[c1] - py[c]);
                vs2 += pz[c] + tt * (pz[c1] - pz[c]);
                cnt += 1.f;
            }
        }
    }

    float v0, v1, v2;
    if (cnt > 0.f) {
        float inv = __builtin_amdgcn_rcpf(cnt);
        v0 = vs0 * inv; v1 = vs1 * inv; v2 = vs2 * inv;
    } else {
        v0 = v1 = v2 = 0.f;
    }
    const float s = 1.0f / 159.0f;
    int lt = threadIdx.x * 3;
    sv[lt + 0] = bf16r((v0 - 1.f) * s);
    sv[lt + 1] = bf16r((v1 - 1.f) * s);
    sv[lt + 2] = bf16r((v2 - 1.f) * s);

    __syncthreads();
    int base = blockIdx.x * 768;
    int lim = NVERT_ELEMS - base;
    if (lim > 768) lim = 768;
    int off = threadIdx.x << 2;
    if (off + 4 <= lim) {
        float4 v = *(const float4*)&sv[off];
        *(float4*)(out + base + off) = v;
    } else if (off < lim) {
        for (int k = off; k < lim; ++k) out[base + k] = sv[k];
    }
}

// quad values (elements 0..3, bf16-rounded floats) for quad q; axis-specialized loads
__device__ __forceinline__ float4 quad_vals(const float* __restrict__ grid, int q) {
    int a = q / APQ;
    int rem = q - a * APQ;
    int q0, q1, q2, q3;
    float g0, g1;
    if (a == 0) {
        int i2 = rem % 160; int r = rem / 160; int i1 = r % 160; int i0 = r / 160;
        int ex = i0, ey = i1 + 1, ez = i2 + 1;          // ex in [0,160]
        int pb = i1 * 160 + i2;
        int a0 = max(ex - 1, 0), a1 = min(ex, 159);
        float g0r = grid[a0 * 25600 + pb], g1r = grid[a1 * 25600 + pb];
        g0 = (ex >= 1)   ? g0r : 1.0f;
        g1 = (ex <= 159) ? g1r : 1.0f;
        int b = (ex * C + ey) * C + ez;
        q0 = b - C - 1; q1 = b - 1; q2 = b; q3 = b - C;
    } else if (a == 1) {
        int i2 = rem % 160; int r = rem / 160; int i1 = r % 161; int i0 = r / 161;
        int ex = i0 + 1, ey = i1, ez = i2 + 1;          // ey in [0,160]
        int pb = (ex - 1) * 25600 + i2;
        int a0 = max(ey - 1, 0), a1 = min(ey, 159);
        float g0r = grid[pb + a0 * 160], g1r = grid[pb + a1 * 160];
        g0 = (ey >= 1)   ? g0r : 1.0f;
        g1 = (ey <= 159) ? g1r : 1.0f;
        int b = (ex * C + ey) * C + ez;
        q0 = b - C * C - 1; q1 = b - 1; q2 = b; q3 = b - C * C;
    } else {
        int i2 = rem % 161; int r = rem / 161; int i1 = r % 160; int i0 = r / 160;
        int ex = i0 + 1, ey = i1 + 1, ez = i2;          // ez in [0,160]
        int pb = ((ex - 1) * 160 + i1) * 160;
        int a0 = max(ez - 1, 0), a1 = min(ez, 159);
        float g0r = grid[pb + a0], g1r = grid[pb + a1];
        g0 = (ez >= 1)   ? g0r : 1.0f;
        g1 = (ez <= 159) ? g1r : 1.0f;
        int b = (ex * C + ey) * C + ez;
        q0 = b - C * C - C; q1 = b - C; q2 = b; q3 = b - C * C;
    }
    float4 w;
    bool m = (g0 < 0.f) != (g1 < 0.f);
    if (!m) {
        w.x = w.y = w.z = w.w = -1.0f;
    } else {
        int a0, a1, a2, a3;
        if (g0 < 0.f) { a0 = q0; a1 = q1; a2 = q2; a3 = q3; }
        else          { a0 = q3; a1 = q2; a2 = q1; a3 = q0; }
        w.x = bf16r((float)a0);
        w.y = bf16r((float)a1);
        w.z = bf16r((float)a2);
        w.w = bf16r((float)a3);
    }
    return w;
}

// Barrier-free quads: thread w owns 16 aligned output elements at
// NVERT+1+16w = quad-element linears 16w+1..16w+16 = quads 4w..4w+3 (full)
// + elem0 of quad 4w+4. 4 independent aligned float4 stores, no LDS.
__global__ __launch_bounds__(256) void quads_kernel(const float* __restrict__ grid,
                                                    float* __restrict__ out) {
    int w = blockIdx.x * 256 + threadIdx.x;
    float* gp = out + NVERT_ELEMS + 1 + ((size_t)w << 4);
    int q = w << 2;

    if (w == 0) out[NVERT_ELEMS] = quad_vals(grid, 0).x;   // head element

    float4 a = quad_vals(grid, q);
    float4 b = quad_vals(grid, q + 1);
    float4 s0; s0.x = a.y; s0.y = a.z; s0.z = a.w; s0.w = b.x;
    *(float4*)(gp + 0) = s0;

    float4 c = quad_vals(grid, q + 2);
    float4 s1; s1.x = b.y; s1.y = b.z; s1.z = b.w; s1.w = c.x;
    *(float4*)(gp + 4) = s1;

    float4 d = quad_vals(grid, q + 3);
    float4 s2; s2.x = c.y; s2.y = c.z; s2.z = c.w; s2.w = d.x;
    *(float4*)(gp + 8) = s2;

    if (w < NW - 1) {
        float4 e = quad_vals(grid, q + 4);
        float4 s3; s3.x = d.y; s3.y = d.z; s3.z = d.w; s3.w = e.x;
        *(float4*)(gp + 12) = s3;
    } else {
        gp[12] = d.y; gp[13] = d.z; gp[14] = d.w;          // last linear = TOTQ-1
    }
}

extern "C" void kernel_launch(void* const* d_in, const int* in_sizes, int n_in,
                              void* d_out, int out_size, void* d_ws, size_t ws_size,
                              hipStream_t stream) {
    const float* grid   = (const float*)d_in[0];
    const float* deform = (const float*)d_in[1];
    float* out = (float*)d_out;

    hipLaunchKernelGGL(verts_kernel, dim3(NVB), dim3(256), 0, stream, grid, deform, out);
    hipLaunchKernelGGL(quads_kernel, dim3(NWB), dim3(256), 0, stream, grid, out);
}

// Round 8
// 97.152 us; speedup vs baseline: 1.7370x; 1.7370x over previous
//
#include <hip/hip_runtime.h>

#define C 161
#define C3 4173281            // 161^3 cells
#define NVERT_ELEMS 12519843  // C3*3
#define APQ 4121600           // 161*160*160 quads per axis
#define TQ 12364800           // 3*APQ
#define TOTQ_ELEMS 49459200   // 4*TQ
#define NVB 16302             // ceil(C3/256)
#define NQB 48300             // TQ/256

// round f32 to nearest bf16 (RNE), return as f32
__device__ __forceinline__ float bf16r(float f) {
    union { float f; unsigned int u; } v; v.f = f;
    v.u += 0x7FFFu + ((v.u >> 16) & 1u);
    v.u &= 0xFFFF0000u;
    return v.f;
}

// general clamped sample of padded grid (pad 1.0); x,y,z padded coords
__device__ __forceinline__ float sampg(const float* __restrict__ g, int x, int y, int z) {
    int ux = x - 1, uy = y - 1, uz = z - 1;
    bool in = ((unsigned)ux < 160u) && ((unsigned)uy < 160u) && ((unsigned)uz < 160u);
    int cx = min(max(ux, 0), 159);
    int cy = min(max(uy, 0), 159);
    int cz = min(max(uz, 0), 159);
    float v = g[(cx * 160 + cy) * 160 + cz];
    return in ? v : 1.0f;
}

__global__ __launch_bounds__(256) void verts_kernel(const float* __restrict__ grid,
                                                    const float* __restrict__ deform,
                                                    float* __restrict__ out) {
    __shared__ __align__(16) float sv[768];
    int tid = blockIdx.x * 256 + threadIdx.x;
    int cz = tid % C;
    int t2 = tid / C;
    int cy = t2 % C;
    int cx = t2 / C;

    float gv[8], px[8], py[8], pz[8];
    // wave-uniform fast path: every lane's 8 corners strictly in-bounds
    bool interior = ((unsigned)(cx - 1) < 159u) & ((unsigned)(cy - 1) < 159u) &
                    ((unsigned)(cz - 1) < 159u);
    if (__all(interior)) {
        int base = ((cx - 1) * 160 + (cy - 1)) * 160 + (cz - 1);
#pragma unroll
        for (int c = 0; c < 8; ++c) {
            int bx = (c >> 2) & 1, by = (c >> 1) & 1, bz = c & 1;
            int idx = base + bx * 25600 + by * 160 + bz;
            gv[c] = grid[idx];
            const float* p = deform + (size_t)idx * 3;
            px[c] = (float)(cx + bx) + p[0];
            py[c] = (float)(cy + by) + p[1];
            pz[c] = (float)(cz + bz) + p[2];
        }
    } else {
#pragma unroll
        for (int c = 0; c < 8; ++c) {
            int bx = (c >> 2) & 1, by = (c >> 1) & 1, bz = c & 1;
            int x = cx + bx, y = cy + by, z = cz + bz;
            gv[c] = sampg(grid, x, y, z);
            int ux = x - 1, uy = y - 1, uz = z - 1;
            bool in = ((unsigned)ux < 160u) && ((unsigned)uy < 160u) && ((unsigned)uz < 160u);
            int ix = min(max(ux, 0), 159);
            int iy = min(max(uy, 0), 159);
            int iz = min(max(uz, 0), 159);
            const float* p = deform + ((size_t)((ix * 160 + iy) * 160 + iz)) * 3;
            float a0 = p[0], a1 = p[1], a2 = p[2];
            px[c] = (float)x + (in ? a0 : 0.f);
            py[c] = (float)y + (in ? a1 : 0.f);
            pz[c] = (float)z + (in ? a2 : 0.f);
        }
    }

    float vs0 = 0.f, vs1 = 0.f, vs2 = 0.f, cnt = 0.f;
#pragma unroll
    for (int a = 0; a < 3; ++a) {
        int step = (a == 0) ? 4 : ((a == 1) ? 2 : 1);
#pragma unroll
        for (int c = 0; c < 8; ++c) {
            if (c & step) continue;
            int c1 = c | step;
            float g0 = gv[c], g1 = gv[c1];
            if ((g0 < 0.f) != (g1 < 0.f)) {
                float tt = g0 * __builtin_amdgcn_rcpf(g0 - g1);
                vs0 += px[c] + tt * (px[c1] - px[c]);
                vs1 += py[c] + tt * (py[c1] - py[c]);
                vs2 += pz[c] + tt * (pz[c1] - pz[c]);
                cnt += 1.f;
            }
        }
    }

    float v0, v1, v2;
    if (cnt > 0.f) {
        float inv = __builtin_amdgcn_rcpf(cnt);
        v0 = vs0 * inv; v1 = vs1 * inv; v2 = vs2 * inv;
    } else {
        v0 = v1 = v2 = 0.f;
    }
    const float s = 1.0f / 159.0f;
    int lt = threadIdx.x * 3;
    sv[lt + 0] = bf16r((v0 - 1.f) * s);
    sv[lt + 1] = bf16r((v1 - 1.f) * s);
    sv[lt + 2] = bf16r((v2 - 1.f) * s);

    __syncthreads();
    int base = blockIdx.x * 768;
    int lim = NVERT_ELEMS - base;
    if (lim > 768) lim = 768;
    int off = threadIdx.x << 2;
    if (off + 4 <= lim) {
        float4 v = *(const float4*)&sv[off];
        *(float4*)(out + base + off) = v;
    } else if (off < lim) {
        for (int k = off; k < lim; ++k) out[base + k] = sv[k];
    }
}

// quad values (elements 0..3, bf16-rounded floats) for quad q; axis-specialized loads
__device__ __forceinline__ float4 quad_vals(const float* __restrict__ grid, int q) {
    int a = q / APQ;
    int rem = q - a * APQ;
    int q0, q1, q2, q3;
    float g0, g1;
    if (a == 0) {
        int i2 = rem % 160; int r = rem / 160; int i1 = r % 160; int i0 = r / 160;
        int ex = i0, ey = i1 + 1, ez = i2 + 1;          // ex in [0,160]
        int pb = i1 * 160 + i2;
        int a0 = max(ex - 1, 0), a1 = min(ex, 159);
        float g0r = grid[a0 * 25600 + pb], g1r = grid[a1 * 25600 + pb];
        g0 = (ex >= 1)   ? g0r : 1.0f;
        g1 = (ex <= 159) ? g1r : 1.0f;
        int b = (ex * C + ey) * C + ez;
        q0 = b - C - 1; q1 = b - 1; q2 = b; q3 = b - C;
    } else if (a == 1) {
        int i2 = rem % 160; int r = rem / 160; int i1 = r % 161; int i0 = r / 161;
        int ex = i0 + 1, ey = i1, ez = i2 + 1;          // ey in [0,160]
        int pb = (ex - 1) * 25600 + i2;
        int a0 = max(ey - 1, 0), a1 = min(ey, 159);
        float g0r = grid[pb + a0 * 160], g1r = grid[pb + a1 * 160];
        g0 = (ey >= 1)   ? g0r : 1.0f;
        g1 = (ey <= 159) ? g1r : 1.0f;
        int b = (ex * C + ey) * C + ez;
        q0 = b - C * C - 1; q1 = b - 1; q2 = b; q3 = b - C * C;
    } else {
        int i2 = rem % 161; int r = rem / 161; int i1 = r % 160; int i0 = r / 160;
        int ex = i0 + 1, ey = i1 + 1, ez = i2;          // ez in [0,160]
        int pb = ((ex - 1) * 160 + i1) * 160;
        int a0 = max(ez - 1, 0), a1 = min(ez, 159);
        float g0r = grid[pb + a0], g1r = grid[pb + a1];
        g0 = (ez >= 1)   ? g0r : 1.0f;
        g1 = (ez <= 159) ? g1r : 1.0f;
        int b = (ex * C + ey) * C + ez;
        q0 = b - C * C - C; q1 = b - C; q2 = b; q3 = b - C * C;
    }
    float4 w;
    bool m = (g0 < 0.f) != (g1 < 0.f);
    if (!m) {
        w.x = w.y = w.z = w.w = -1.0f;
    } else {
        int a0, a1, a2, a3;
        if (g0 < 0.f) { a0 = q0; a1 = q1; a2 = q2; a3 = q3; }
        else          { a0 = q3; a1 = q2; a2 = q1; a3 = q0; }
        w.x = bf16r((float)a0);
        w.y = bf16r((float)a1);
        w.z = bf16r((float)a2);
        w.w = bf16r((float)a3);
    }
    return w;
}

// Barrier-free, LDS-free quads with contiguous per-instruction coalescing:
// thread q stores float4 {y,z,w, next.x} at NVERT+1+4q (aligned, lane
// stride 16B). next.x via __shfl_down(1); lane 63 recomputes it.
__global__ __launch_bounds__(256) void quads_kernel(const float* __restrict__ grid,
                                                    float* __restrict__ out) {
    int q = blockIdx.x * 256 + threadIdx.x;
    float4 w = quad_vals(grid, q);

    float nx = __shfl_down(w.x, 1, 64);
    int lane = threadIdx.x & 63;
    if (lane == 63 && q + 1 < TQ) nx = quad_vals(grid, q + 1).x;

    if (q == 0) out[NVERT_ELEMS] = w.x;   // head element (quad0 elem0)

    float* gp = out + NVERT_ELEMS + 1 + ((size_t)q << 2);
    if (q < TQ - 1) {
        float4 s; s.x = w.y; s.y = w.z; s.z = w.w; s.w = nx;
        *(float4*)gp = s;
    } else {
        gp[0] = w.y; gp[1] = w.z; gp[2] = w.w;   // last 3 elements
    }
}

extern "C" void kernel_launch(void* const* d_in, const int* in_sizes, int n_in,
                              void* d_out, int out_size, void* d_ws, size_t ws_size,
                              hipStream_t stream) {
    const float* grid   = (const float*)d_in[0];
    const float* deform = (const float*)d_in[1];
    float* out = (float*)d_out;

    hipLaunchKernelGGL(verts_kernel, dim3(NVB), dim3(256), 0, stream, grid, deform, out);
    hipLaunchKernelGGL(quads_kernel, dim3(NQB), dim3(256), 0, stream, grid, out);
}